// Round 1
// baseline (407.107 us; speedup 1.0000x reference)
//
#include <hip/hip_runtime.h>
#include <hip/hip_bf16.h>

typedef __attribute__((ext_vector_type(8))) short short8;   // 8 bf16 (4 VGPRs)
typedef __attribute__((ext_vector_type(4))) float f32x4;    // MFMA acc

#define NH   4
#define NB   1024
#define NL   200
#define NDQ  512
#define NDF  128
#define ND1  128
#define ND2  64
#define KP   136            // padded k-stride (bf16 elems) -> 272B rows (16B-aligned)

// workspace layout (bytes)
#define OFF_WQC   0                                    // fp32 [H][512][64]   524288
#define OFF_BQC   (NH*NDQ*ND2*4)                       // fp32 [H][64]
#define OFF_FQ    (OFF_BQC + NH*ND2*4)                 // fp32 [H][B][64]
#define OFF_WIMG  (OFF_FQ + NH*NB*ND2*4)               // bf16 [H][3][64][KP] (slots: Wf_hi, Wf_lo, Wv_hi)
#define OFF_BFC   (OFF_WIMG + NH*3*ND2*KP*2)           // fp32 [H][64]
#define OFF_BVC   (OFF_BFC + NH*ND2*4)                 // fp32 [H][64]

__device__ inline short f2bf(float f) {                // RN-even fp32 -> bf16 bits
    union { float f; unsigned u; } v; v.f = f;
    unsigned r = (v.u + 0x7FFFu + ((v.u >> 16) & 1u)) >> 16;
    return (short)r;
}
__device__ inline float bf2f(short s) {
    union { unsigned u; float f; } v; v.u = ((unsigned)(unsigned short)s) << 16;
    return v.f;
}
__device__ inline float fsilu(float z) {               // fast silu
    return z * __fdividef(1.f, 1.f + __expf(-z));
}

// ---------------- K1: fuse weights (identity between FC layers) ----------------
__global__ __launch_bounds__(256) void k_combine(
    const float* __restrict__ Wq1, const float* __restrict__ bq1,
    const float* __restrict__ Wq2, const float* __restrict__ bq2,
    const float* __restrict__ Wf1, const float* __restrict__ bf1,
    const float* __restrict__ Wf2, const float* __restrict__ bf2,
    const float* __restrict__ Wv1, const float* __restrict__ bv1,
    const float* __restrict__ Wv2, const float* __restrict__ bv2,
    float* __restrict__ WQC, float* __restrict__ BQC,
    __hip_bfloat16* __restrict__ WIMG, float* __restrict__ BFC, float* __restrict__ BVC)
{
    int g = blockIdx.x * 256 + threadIdx.x;
    if (g < NH*NDQ*ND2) {                       // Wqc = Wq1@Wq2 (fp32 exact)
        int h = g >> 15, r = g & 32767, i = r >> 6, j = r & 63;
        const float* a  = Wq1 + (h*NDQ + i)*ND1;
        const float* bb = Wq2 + h*ND1*ND2 + j;
        float s = 0.f;
        for (int k = 0; k < ND1; ++k) s += a[k] * bb[k*ND2];
        WQC[(h*NDQ + i)*ND2 + j] = s;
        return;
    }
    g -= NH*NDQ*ND2;
    if (g < 2*NH*NDF*ND2) {                     // Wfc (hi+lo) / Wvc (hi), transposed+padded image
        int which = (g >= NH*NDF*ND2);
        int r0 = g & (NH*NDF*ND2 - 1);
        int h = r0 >> 13, r = r0 & 8191, i = r >> 6, j = r & 63;
        const float* W1 = (which ? Wv1 : Wf1) + (h*NDF + i)*ND1;
        const float* W2 = (which ? Wv2 : Wf2) + h*ND1*ND2 + j;
        float s = 0.f;
        for (int k = 0; k < ND1; ++k) s += W1[k] * W2[k*ND2];
        short hi = f2bf(s);
        short lo = f2bf(s - bf2f(hi));
        __hip_bfloat16* img = WIMG + (size_t)((h*3 + (which ? 2 : 0))*ND2 + j)*KP + i; // [col=j][k=i]
        ((short*)img)[0] = hi;
        if (!which) ((short*)img)[ND2*KP] = lo;  // Wf lo slot
        return;
    }
    g -= 2*NH*NDF*ND2;
    if (g < NH*ND2) {                           // bqc = bq1@Wq2 + bq2
        int h = g >> 6, j = g & 63;
        float s = bq2[h*ND2 + j];
        for (int k = 0; k < ND1; ++k) s += bq1[h*ND1 + k] * Wq2[(h*ND1 + k)*ND2 + j];
        BQC[g] = s; return;
    }
    g -= NH*ND2;
    if (g < NH*ND2) {
        int h = g >> 6, j = g & 63;
        float s = bf2[h*ND2 + j];
        for (int k = 0; k < ND1; ++k) s += bf1[h*ND1 + k] * Wf2[(h*ND1 + k)*ND2 + j];
        BFC[g] = s; return;
    }
    g -= NH*ND2;
    if (g < NH*ND2) {
        int h = g >> 6, j = g & 63;
        float s = bv2[h*ND2 + j];
        for (int k = 0; k < ND1; ++k) s += bv1[h*ND1 + k] * Wv2[(h*ND1 + k)*ND2 + j];
        BVC[g] = s; return;
    }
}

// ---------------- K2: fq = silu(q @ Wqc + bqc) ----------------
// 512 blocks x 2 batches; t -> (h = t>>6, d = t&63). 2x wave count vs 4-batch
// version -> TLP actually hides the strided L2 read latency.
__global__ __launch_bounds__(256) void k_fq(
    const float* __restrict__ query, const float* __restrict__ WQC,
    const float* __restrict__ BQC, float* __restrict__ FQ)
{
    __shared__ __align__(16) float qS[2*NDQ];
    const int t = threadIdx.x;
    const int b0 = blockIdx.x * 2;
    {
        const float4* src = (const float4*)(query + (size_t)b0 * NDQ);
        ((float4*)qS)[t] = src[t];              // 256 float4 = 2 x 512 floats
    }
    __syncthreads();
    const int h = t >> 6, d = t & 63;
    float s0, s1;
    s0 = s1 = BQC[h*ND2 + d];
    const float* wp = WQC + (size_t)h*NDQ*ND2 + d;
    #pragma unroll 16
    for (int i = 0; i < NDQ; ++i) {
        float wv = wp[i*ND2];
        s0 += qS[i]       * wv;
        s1 += qS[NDQ + i] * wv;
    }
    float* o = FQ + ((size_t)h*NB + b0)*ND2 + d;
    o[0]   = fsilu(s0);
    o[ND2] = fsilu(s1);
}

// ---------------- K3: main fused attention ----------------
// 512 threads (8 warps). Warp w owns M-tiles {w, w+8} (13 tiles total).
// Per head: [stage -> barrier] -> ff GEMM + logits + WARP-LOCAL softmax
// -> fv GEMM + AV with per-warp (m, s, oE, oS) -> barrier -> LSE-merge by 64
// threads (overlapped with next head's staging). 2 barriers/head (was 3),
// no dotS round-trip, no 8x-redundant 200-row softmax, no alpha recompute.
__global__ __launch_bounds__(512, 4) void k_main(
    const float* __restrict__ fact,
    const int* __restrict__ mask,
    const float* __restrict__ mmc,
    const float* __restrict__ tau1,
    const float* __restrict__ tau2,
    const float* __restrict__ FQ,
    const float* __restrict__ BFC,
    const float* __restrict__ BVC,
    const __hip_bfloat16* __restrict__ WIMG,
    float* __restrict__ out)
{
    __shared__ __align__(16) __hip_bfloat16 wS[3*ND2*KP];   // 52224 B: Wf_hi, Wf_lo, Wv_hi
    __shared__ __align__(16) float pS[8][132];              // per warp: m, s, oE[64], oS[64]

    const int t    = threadIdx.x;
    const int b    = blockIdx.x;
    const int w    = t >> 6;
    const int lane = t & 63;
    const int a15  = lane & 15;
    const int quad = lane >> 4;
    const int nmt  = (w < 5) ? 2 : 1;           // 13 M-tiles over 8 warps

    // A fragments: fact[b] split hi/lo bf16, resident in registers for all heads.
    short8 afh[2][4], afl[2][4];
    const short8 zero8 = {0,0,0,0,0,0,0,0};
    for (int mi = 0; mi < 2; ++mi) {
        int mt = w + 8*mi;
        int row = mt*16 + a15;
        for (int kk = 0; kk < 4; ++kk) {
            short8 vh = zero8, vl = zero8;
            if (mt < 13 && row < NL) {
                const float* p = fact + ((size_t)(b*NL + row))*NDF + kk*32 + quad*8;
                float4 x0 = *(const float4*)p;
                float4 x1 = *(const float4*)(p + 4);
                float v[8] = {x0.x, x0.y, x0.z, x0.w, x1.x, x1.y, x1.z, x1.w};
                for (int j = 0; j < 8; ++j) {
                    short hs = f2bf(v[j]);
                    vh[j] = hs;
                    vl[j] = f2bf(v[j] - bf2f(hs));
                }
            }
            afh[mi][kk] = vh;
            afl[mi][kk] = vl;
        }
    }

    const int bL = b * NL;
    const f32x4 zf = {0.f, 0.f, 0.f, 0.f};

    // stage head 0
    {
        const float4* src = (const float4*)(WIMG);
        float4* dst = (float4*)wS;
        for (int i = t; i < 3264; i += 512) dst[i] = src[i];
    }
    __syncthreads();

    for (int h = 0; h < NH; ++h) {
        const float rt1a = __fdividef(1.f, tau1[h]);
        const float rt1b = __fdividef(1.f, tau1[NH + h]);
        const float t20 = tau2[h];
        const float t21 = tau2[NH + h];
        const float t22 = tau2[2*NH + h];

        // ---- ff GEMM, 3 passes: f_hi*w_hi + f_hi*w_lo + f_lo*w_hi ----
        f32x4 acc[2][4];
        for (int mi = 0; mi < 2; ++mi) for (int nt = 0; nt < 4; ++nt) acc[mi][nt] = zf;
        __builtin_amdgcn_s_setprio(1);
        for (int kk = 0; kk < 4; ++kk) {
            short8 bh[4], bl[4];
            for (int nt = 0; nt < 4; ++nt) {
                const __hip_bfloat16* p = wS + (nt*16 + a15)*KP + kk*32 + quad*8;
                bh[nt] = *(const short8*)p;
                bl[nt] = *(const short8*)(p + ND2*KP);
            }
            for (int mi = 0; mi < 2; ++mi)
                if (mi < nmt)
                    for (int nt = 0; nt < 4; ++nt) {
                        acc[mi][nt] = __builtin_amdgcn_mfma_f32_16x16x32_bf16(afh[mi][kk], bh[nt], acc[mi][nt], 0, 0, 0);
                        acc[mi][nt] = __builtin_amdgcn_mfma_f32_16x16x32_bf16(afh[mi][kk], bl[nt], acc[mi][nt], 0, 0, 0);
                        acc[mi][nt] = __builtin_amdgcn_mfma_f32_16x16x32_bf16(afl[mi][kk], bh[nt], acc[mi][nt], 0, 0, 0);
                    }
        }
        __builtin_amdgcn_s_setprio(0);

        // ---- epilogue: silu, dot with fq (butterfly leaves row-dot in ALL lanes),
        //      then mask + cosine bias -> logits for this warp's own rows ----
        float fqv[4], bfcv[4];
        for (int nt = 0; nt < 4; ++nt) {
            int col = nt*16 + a15;
            fqv[nt]  = FQ[((size_t)h*NB + b)*ND2 + col];
            bfcv[nt] = BFC[h*ND2 + col];
        }
        float lg[2][4];
        for (int mi = 0; mi < 2; ++mi)
            for (int rg = 0; rg < 4; ++rg) {
                float l = -3.0e38f;
                if (mi < nmt) {
                    float s = 0.f;
                    for (int nt = 0; nt < 4; ++nt)
                        s += fsilu(acc[mi][nt][rg] + bfcv[nt]) * fqv[nt];
                    s += __shfl_xor(s, 1);
                    s += __shfl_xor(s, 2);
                    s += __shfl_xor(s, 4);
                    s += __shfl_xor(s, 8);
                    int r = (w + 8*mi)*16 + quad*4 + rg;
                    if (r < NL) {
                        float dv = s - 1e9f * (1.0f - (float)mask[bL + r]);
                        float bias = mmc[bL + r]*rt1a + mmc[NB*NL + bL + r]*rt1b;
                        l = t20*dv + t21*bias + t22*dv*bias;
                    }
                }
                lg[mi][rg] = l;
            }

        // ---- warp-local softmax over own rows (quads combined via xor16/32) ----
        float m = lg[0][0];
        m = fmaxf(m, lg[0][1]); m = fmaxf(m, lg[0][2]); m = fmaxf(m, lg[0][3]);
        m = fmaxf(m, lg[1][0]); m = fmaxf(m, lg[1][1]);
        m = fmaxf(m, lg[1][2]); m = fmaxf(m, lg[1][3]);
        m = fmaxf(m, __shfl_xor(m, 16));
        m = fmaxf(m, __shfl_xor(m, 32));
        float sw = 0.f;
        for (int mi = 0; mi < 2; ++mi)
            for (int rg = 0; rg < 4; ++rg) {
                float p = __expf(lg[mi][rg] - m);   // invalid rows underflow to 0
                lg[mi][rg] = p;
                sw += p;
            }
        sw += __shfl_xor(sw, 16);
        sw += __shfl_xor(sw, 32);

        // ---- fv GEMM: single hi*hi pass (slot 2), reuse acc ----
        for (int mi = 0; mi < 2; ++mi) for (int nt = 0; nt < 4; ++nt) acc[mi][nt] = zf;
        __builtin_amdgcn_s_setprio(1);
        for (int kk = 0; kk < 4; ++kk) {
            short8 bh[4];
            for (int nt = 0; nt < 4; ++nt)
                bh[nt] = *(const short8*)(wS + (2*ND2 + nt*16 + a15)*KP + kk*32 + quad*8);
            for (int mi = 0; mi < 2; ++mi)
                if (mi < nmt)
                    for (int nt = 0; nt < 4; ++nt)
                        acc[mi][nt] = __builtin_amdgcn_mfma_f32_16x16x32_bf16(afh[mi][kk], bh[nt], acc[mi][nt], 0, 0, 0);
        }
        __builtin_amdgcn_s_setprio(0);

        // ---- AV: oE = sum p*silu(fv), oS = sum silu(fv) (for the +1e-7 term) ----
        float bvcv[4];
        for (int nt = 0; nt < 4; ++nt) bvcv[nt] = BVC[h*ND2 + nt*16 + a15];
        float oE[4] = {0.f,0.f,0.f,0.f}, oS[4] = {0.f,0.f,0.f,0.f};
        for (int mi = 0; mi < 2; ++mi)
            if (mi < nmt)
                for (int rg = 0; rg < 4; ++rg) {
                    float p = lg[mi][rg];
                    int r = (w + 8*mi)*16 + quad*4 + rg;
                    float vm = (r < NL) ? 1.f : 0.f;
                    for (int nt = 0; nt < 4; ++nt) {
                        float sv = fsilu(acc[mi][nt][rg] + bvcv[nt]);
                        oE[nt] += p * sv;
                        oS[nt] += vm * sv;
                    }
                }
        for (int nt = 0; nt < 4; ++nt) {
            oE[nt] += __shfl_xor(oE[nt], 16);
            oE[nt] += __shfl_xor(oE[nt], 32);
            oS[nt] += __shfl_xor(oS[nt], 16);
            oS[nt] += __shfl_xor(oS[nt], 32);
        }
        if (lane == 0) { pS[w][0] = m; pS[w][1] = sw; }
        if (quad == 0)
            for (int nt = 0; nt < 4; ++nt) {
                pS[w][2  + nt*16 + a15] = oE[nt];
                pS[w][66 + nt*16 + a15] = oS[nt];
            }
        __syncthreads();                        // pS ready; all wS reads done

        // stage next head's weights (overlaps the merge below)
        if (h + 1 < NH) {
            const float4* src = (const float4*)(WIMG + (size_t)((h+1)*3)*ND2*KP);
            float4* dst = (float4*)wS;
            for (int i = t; i < 3264; i += 512) dst[i] = src[i];
        }
        // LSE-merge of 8 warps, write output for this head
        if (t < 64) {
            float M = pS[0][0];
            for (int ww = 1; ww < 8; ++ww) M = fmaxf(M, pS[ww][0]);
            float den = 0.f, num = 0.f, s1 = 0.f;
            for (int ww = 0; ww < 8; ++ww) {
                float e = __expf(pS[ww][0] - M);
                den += e * pS[ww][1];
                num += e * pS[ww][2 + t];
                s1  += pS[ww][66 + t];
            }
            out[(size_t)b*(NH*ND2) + h*ND2 + t] = num * __fdividef(1.f, den) + 1e-7f * s1;
        }
        __syncthreads();                        // wS staged & merge done
    }
}

extern "C" void kernel_launch(void* const* d_in, const int* in_sizes, int n_in,
                              void* d_out, int out_size, void* d_ws, size_t ws_size,
                              hipStream_t stream) {
    const float* query = (const float*)d_in[0];
    const float* fact  = (const float*)d_in[1];
    const int*   maskp = (const int*)d_in[2];
    const float* mmc   = (const float*)d_in[3];
    const float* Wq1 = (const float*)d_in[4];
    const float* bq1 = (const float*)d_in[5];
    const float* Wq2 = (const float*)d_in[6];
    const float* bq2 = (const float*)d_in[7];
    const float* Wf1 = (const float*)d_in[8];
    const float* bf1 = (const float*)d_in[9];
    const float* Wf2 = (const float*)d_in[10];
    const float* bf2 = (const float*)d_in[11];
    const float* Wv1 = (const float*)d_in[12];
    const float* bv1 = (const float*)d_in[13];
    const float* Wv2 = (const float*)d_in[14];
    const float* bv2 = (const float*)d_in[15];
    const float* tau1 = (const float*)d_in[16];
    const float* tau2 = (const float*)d_in[17];

    char* ws = (char*)d_ws;
    float*          WQC  = (float*)(ws + OFF_WQC);
    float*          BQC  = (float*)(ws + OFF_BQC);
    float*          FQ   = (float*)(ws + OFF_FQ);
    __hip_bfloat16* WIMG = (__hip_bfloat16*)(ws + OFF_WIMG);
    float*          BFC  = (float*)(ws + OFF_BFC);
    float*          BVC  = (float*)(ws + OFF_BVC);

    k_combine<<<771, 256, 0, stream>>>(Wq1, bq1, Wq2, bq2, Wf1, bf1, Wf2, bf2,
                                       Wv1, bv1, Wv2, bv2, WQC, BQC, WIMG, BFC, BVC);
    k_fq<<<NB/2, 256, 0, stream>>>(query, WQC, BQC, FQ);
    k_main<<<NB, 512, 0, stream>>>(fact, maskp, mmc, tau1, tau2, FQ, BFC, BVC, WIMG,
                                   (float*)d_out);
}

// Round 2
// 349.267 us; speedup vs baseline: 1.1656x; 1.1656x over previous
//
#include <hip/hip_runtime.h>
#include <hip/hip_bf16.h>

typedef __attribute__((ext_vector_type(8))) short short8;   // 8 bf16 (4 VGPRs)
typedef __attribute__((ext_vector_type(4))) float f32x4;    // MFMA acc

#define NH   4
#define NB   1024
#define NL   200
#define NDQ  512
#define NDF  128
#define ND1  128
#define ND2  64
#define KP   136            // padded k-stride (bf16 elems) -> 272B rows (16B-aligned)
#define NW   13             // active warps = M-tiles (13*16 = 208 >= 200 rows)
#define NT   (NW*64)        // 832 threads

// workspace layout (bytes)
#define OFF_WQC   0                                    // fp32 [H][512][64]   524288
#define OFF_BQC   (NH*NDQ*ND2*4)                       // fp32 [H][64]
#define OFF_FQ    (OFF_BQC + NH*ND2*4)                 // fp32 [H][B][64]
#define OFF_WIMG  (OFF_FQ + NH*NB*ND2*4)               // bf16 [H][3][64][KP] (slots: Wf_hi, Wf_lo, Wv_hi)
#define OFF_BFC   (OFF_WIMG + NH*3*ND2*KP*2)           // fp32 [H][64]
#define OFF_BVC   (OFF_BFC + NH*ND2*4)                 // fp32 [H][64]

__device__ inline short f2bf(float f) {                // RN-even fp32 -> bf16 bits
    union { float f; unsigned u; } v; v.f = f;
    unsigned r = (v.u + 0x7FFFu + ((v.u >> 16) & 1u)) >> 16;
    return (short)r;
}
__device__ inline float bf2f(short s) {
    union { unsigned u; float f; } v; v.u = ((unsigned)(unsigned short)s) << 16;
    return v.f;
}
__device__ inline float fsilu(float z) {               // fast silu
    return z * __fdividef(1.f, 1.f + __expf(-z));
}

// ---------------- K1: fuse weights (identity between FC layers) ----------------
__global__ __launch_bounds__(256) void k_combine(
    const float* __restrict__ Wq1, const float* __restrict__ bq1,
    const float* __restrict__ Wq2, const float* __restrict__ bq2,
    const float* __restrict__ Wf1, const float* __restrict__ bf1,
    const float* __restrict__ Wf2, const float* __restrict__ bf2,
    const float* __restrict__ Wv1, const float* __restrict__ bv1,
    const float* __restrict__ Wv2, const float* __restrict__ bv2,
    float* __restrict__ WQC, float* __restrict__ BQC,
    __hip_bfloat16* __restrict__ WIMG, float* __restrict__ BFC, float* __restrict__ BVC)
{
    int g = blockIdx.x * 256 + threadIdx.x;
    if (g < NH*NDQ*ND2) {                       // Wqc = Wq1@Wq2 (fp32 exact)
        int h = g >> 15, r = g & 32767, i = r >> 6, j = r & 63;
        const float* a  = Wq1 + (h*NDQ + i)*ND1;
        const float* bb = Wq2 + h*ND1*ND2 + j;
        float s = 0.f;
        for (int k = 0; k < ND1; ++k) s += a[k] * bb[k*ND2];
        WQC[(h*NDQ + i)*ND2 + j] = s;
        return;
    }
    g -= NH*NDQ*ND2;
    if (g < 2*NH*NDF*ND2) {                     // Wfc (hi+lo) / Wvc (hi), transposed+padded image
        int which = (g >= NH*NDF*ND2);
        int r0 = g & (NH*NDF*ND2 - 1);
        int h = r0 >> 13, r = r0 & 8191, i = r >> 6, j = r & 63;
        const float* W1 = (which ? Wv1 : Wf1) + (h*NDF + i)*ND1;
        const float* W2 = (which ? Wv2 : Wf2) + h*ND1*ND2 + j;
        float s = 0.f;
        for (int k = 0; k < ND1; ++k) s += W1[k] * W2[k*ND2];
        short hi = f2bf(s);
        short lo = f2bf(s - bf2f(hi));
        __hip_bfloat16* img = WIMG + (size_t)((h*3 + (which ? 2 : 0))*ND2 + j)*KP + i; // [col=j][k=i]
        ((short*)img)[0] = hi;
        if (!which) ((short*)img)[ND2*KP] = lo;  // Wf lo slot
        return;
    }
    g -= 2*NH*NDF*ND2;
    if (g < NH*ND2) {                           // bqc = bq1@Wq2 + bq2
        int h = g >> 6, j = g & 63;
        float s = bq2[h*ND2 + j];
        for (int k = 0; k < ND1; ++k) s += bq1[h*ND1 + k] * Wq2[(h*ND1 + k)*ND2 + j];
        BQC[g] = s; return;
    }
    g -= NH*ND2;
    if (g < NH*ND2) {
        int h = g >> 6, j = g & 63;
        float s = bf2[h*ND2 + j];
        for (int k = 0; k < ND1; ++k) s += bf1[h*ND1 + k] * Wf2[(h*ND1 + k)*ND2 + j];
        BFC[g] = s; return;
    }
    g -= NH*ND2;
    if (g < NH*ND2) {
        int h = g >> 6, j = g & 63;
        float s = bv2[h*ND2 + j];
        for (int k = 0; k < ND1; ++k) s += bv1[h*ND1 + k] * Wv2[(h*ND1 + k)*ND2 + j];
        BVC[g] = s; return;
    }
}

// ---------------- K2: fq = silu(q @ Wqc + bqc) ----------------
__global__ __launch_bounds__(256) void k_fq(
    const float* __restrict__ query, const float* __restrict__ WQC,
    const float* __restrict__ BQC, float* __restrict__ FQ)
{
    __shared__ __align__(16) float qS[2*NDQ];
    const int t = threadIdx.x;
    const int b0 = blockIdx.x * 2;
    {
        const float4* src = (const float4*)(query + (size_t)b0 * NDQ);
        ((float4*)qS)[t] = src[t];              // 256 float4 = 2 x 512 floats
    }
    __syncthreads();
    const int h = t >> 6, d = t & 63;
    float s0, s1;
    s0 = s1 = BQC[h*ND2 + d];
    const float* wp = WQC + (size_t)h*NDQ*ND2 + d;
    #pragma unroll 16
    for (int i = 0; i < NDQ; ++i) {
        float wv = wp[i*ND2];
        s0 += qS[i]       * wv;
        s1 += qS[NDQ + i] * wv;
    }
    float* o = FQ + ((size_t)h*NB + b0)*ND2 + d;
    o[0]   = fsilu(s0);
    o[ND2] = fsilu(s1);
}

// ---------------- K3: main fused attention ----------------
// 832 threads (13 warps), ONE M-tile per warp. Halves the A-fragment register
// footprint (32 VGPR vs 64) so the whole kernel fits in <=128 regs WITHOUT
// spilling (round-1's forced-64 cap caused 370 MB of scratch traffic), while
// 13 waves/CU co-reside (vs 8). Per head: ff GEMM + logits + warp-local
// softmax -> fv GEMM + AV -> barrier -> LSE-merge of 13 warps (overlapped
// with next head's weight staging) -> barrier. 2 barriers/head.
__global__ __launch_bounds__(NT) void k_main(
    const float* __restrict__ fact,
    const int* __restrict__ mask,
    const float* __restrict__ mmc,
    const float* __restrict__ tau1,
    const float* __restrict__ tau2,
    const float* __restrict__ FQ,
    const float* __restrict__ BFC,
    const float* __restrict__ BVC,
    const __hip_bfloat16* __restrict__ WIMG,
    float* __restrict__ out)
{
    __shared__ __align__(16) __hip_bfloat16 wS[3*ND2*KP];   // 52224 B: Wf_hi, Wf_lo, Wv_hi
    __shared__ __align__(16) float pS[NW][132];             // per warp: m, s, oE[64], oS[64]

    const int t    = threadIdx.x;
    const int b    = blockIdx.x;
    const int w    = t >> 6;                    // 0..12 = M-tile index
    const int lane = t & 63;
    const int a15  = lane & 15;
    const int quad = lane >> 4;
    const bool act = (w < NW);                  // (always true; keeps guards uniform)

    const int bL = b * NL;

    // A fragments: this warp's 16 fact rows, hi/lo bf16, resident for all heads.
    short8 afh[4], afl[4];
    const short8 zero8 = {0,0,0,0,0,0,0,0};
    {
        int row = w*16 + a15;
        for (int kk = 0; kk < 4; ++kk) {
            short8 vh = zero8, vl = zero8;
            if (act && row < NL) {
                const float* p = fact + ((size_t)(bL + row))*NDF + kk*32 + quad*8;
                float4 x0 = *(const float4*)p;
                float4 x1 = *(const float4*)(p + 4);
                float v[8] = {x0.x, x0.y, x0.z, x0.w, x1.x, x1.y, x1.z, x1.w};
                for (int j = 0; j < 8; ++j) {
                    short hs = f2bf(v[j]);
                    vh[j] = hs;
                    vl[j] = f2bf(v[j] - bf2f(hs));
                }
            }
            afh[kk] = vh;
            afl[kk] = vl;
        }
    }

    // hoist head-invariant per-row data (mask penalty + cosine terms)
    float mkv[4], c0v[4], c1v[4];
    {
        int rbase = w*16 + quad*4;
        for (int rg = 0; rg < 4; ++rg) {
            int r = rbase + rg;
            if (act && r < NL) {
                mkv[rg] = 1e9f * (1.0f - (float)mask[bL + r]);
                c0v[rg] = mmc[bL + r];
                c1v[rg] = mmc[NB*NL + bL + r];
            } else { mkv[rg] = 0.f; c0v[rg] = 0.f; c1v[rg] = 0.f; }
        }
    }

    const f32x4 zf = {0.f, 0.f, 0.f, 0.f};

    // stage head 0 weights
    {
        const float4* src = (const float4*)(WIMG);
        float4* dst = (float4*)wS;
        for (int i = t; i < 3264; i += NT) dst[i] = src[i];
    }
    __syncthreads();

    for (int h = 0; h < NH; ++h) {
        const float rt1a = __fdividef(1.f, tau1[h]);
        const float rt1b = __fdividef(1.f, tau1[NH + h]);
        const float t20 = tau2[h];
        const float t21 = tau2[NH + h];
        const float t22 = tau2[2*NH + h];

        float fqv[4], bfcv[4];
        for (int nt = 0; nt < 4; ++nt) {
            int col = nt*16 + a15;
            fqv[nt]  = FQ[((size_t)h*NB + b)*ND2 + col];
            bfcv[nt] = BFC[h*ND2 + col];
        }

        // ---- ff GEMM, 3 passes: f_hi*w_hi + f_hi*w_lo + f_lo*w_hi ----
        f32x4 acc[4];
        for (int nt = 0; nt < 4; ++nt) acc[nt] = zf;
        if (act) {
            __builtin_amdgcn_s_setprio(1);
            for (int kk = 0; kk < 4; ++kk) {
                short8 bh[4], bl[4];
                for (int nt = 0; nt < 4; ++nt) {
                    const __hip_bfloat16* p = wS + (nt*16 + a15)*KP + kk*32 + quad*8;
                    bh[nt] = *(const short8*)p;
                    bl[nt] = *(const short8*)(p + ND2*KP);
                }
                for (int nt = 0; nt < 4; ++nt) {
                    acc[nt] = __builtin_amdgcn_mfma_f32_16x16x32_bf16(afh[kk], bh[nt], acc[nt], 0, 0, 0);
                    acc[nt] = __builtin_amdgcn_mfma_f32_16x16x32_bf16(afh[kk], bl[nt], acc[nt], 0, 0, 0);
                    acc[nt] = __builtin_amdgcn_mfma_f32_16x16x32_bf16(afl[kk], bh[nt], acc[nt], 0, 0, 0);
                }
            }
            __builtin_amdgcn_s_setprio(0);
        }

        // ---- epilogue: silu, dot with fq (butterfly leaves row-dot in all 16
        //      lanes of each quad-group), mask + cosine bias -> logits ----
        float lg[4];
        for (int rg = 0; rg < 4; ++rg) {
            float l = -3.0e38f;
            if (act) {
                float s = 0.f;
                for (int nt = 0; nt < 4; ++nt)
                    s += fsilu(acc[nt][rg] + bfcv[nt]) * fqv[nt];
                s += __shfl_xor(s, 1);
                s += __shfl_xor(s, 2);
                s += __shfl_xor(s, 4);
                s += __shfl_xor(s, 8);
                int r = w*16 + quad*4 + rg;
                if (r < NL) {
                    float dv = s - mkv[rg];
                    float bias = c0v[rg]*rt1a + c1v[rg]*rt1b;
                    l = t20*dv + t21*bias + t22*dv*bias;
                }
            }
            lg[rg] = l;
        }

        // ---- warp-local softmax over own 16 rows ----
        float m = fmaxf(fmaxf(lg[0], lg[1]), fmaxf(lg[2], lg[3]));
        m = fmaxf(m, __shfl_xor(m, 16));
        m = fmaxf(m, __shfl_xor(m, 32));
        float sw = 0.f;
        for (int rg = 0; rg < 4; ++rg) {
            float p = __expf(lg[rg] - m);       // invalid rows underflow to 0
            lg[rg] = p;
            sw += p;
        }
        sw += __shfl_xor(sw, 16);
        sw += __shfl_xor(sw, 32);

        // ---- fv GEMM: single hi*hi pass (slot 2), reuse acc ----
        for (int nt = 0; nt < 4; ++nt) acc[nt] = zf;
        if (act) {
            __builtin_amdgcn_s_setprio(1);
            for (int kk = 0; kk < 4; ++kk) {
                short8 bh[4];
                for (int nt = 0; nt < 4; ++nt)
                    bh[nt] = *(const short8*)(wS + (2*ND2 + nt*16 + a15)*KP + kk*32 + quad*8);
                for (int nt = 0; nt < 4; ++nt)
                    acc[nt] = __builtin_amdgcn_mfma_f32_16x16x32_bf16(afh[kk], bh[nt], acc[nt], 0, 0, 0);
            }
            __builtin_amdgcn_s_setprio(0);
        }

        // ---- AV: oE = sum p*silu(fv), oS = sum silu(fv) (for the +1e-7 term) ----
        float bvcv[4];
        for (int nt = 0; nt < 4; ++nt) bvcv[nt] = BVC[h*ND2 + nt*16 + a15];
        float oE[4] = {0.f,0.f,0.f,0.f}, oS[4] = {0.f,0.f,0.f,0.f};
        if (act)
            for (int rg = 0; rg < 4; ++rg) {
                float p = lg[rg];
                int r = w*16 + quad*4 + rg;
                float vm = (r < NL) ? 1.f : 0.f;
                for (int nt = 0; nt < 4; ++nt) {
                    float sv = fsilu(acc[nt][rg] + bvcv[nt]);
                    oE[nt] += p * sv;
                    oS[nt] += vm * sv;
                }
            }
        for (int nt = 0; nt < 4; ++nt) {
            oE[nt] += __shfl_xor(oE[nt], 16);
            oE[nt] += __shfl_xor(oE[nt], 32);
            oS[nt] += __shfl_xor(oS[nt], 16);
            oS[nt] += __shfl_xor(oS[nt], 32);
        }
        if (act) {
            if (lane == 0) { pS[w][0] = m; pS[w][1] = sw; }
            if (quad == 0)
                for (int nt = 0; nt < 4; ++nt) {
                    pS[w][2  + nt*16 + a15] = oE[nt];
                    pS[w][66 + nt*16 + a15] = oS[nt];
                }
        }
        __syncthreads();                        // pS ready; all wS reads done

        // stage next head's weights (overlaps the merge below)
        if (h + 1 < NH) {
            const float4* src = (const float4*)(WIMG + (size_t)((h+1)*3)*ND2*KP);
            float4* dst = (float4*)wS;
            for (int i = t; i < 3264; i += NT) dst[i] = src[i];
        }
        // LSE-merge of 13 warps, write output for this head
        if (t < 64) {
            float M = pS[0][0];
            for (int ww = 1; ww < NW; ++ww) M = fmaxf(M, pS[ww][0]);
            float den = 0.f, num = 0.f, s1 = 0.f;
            for (int ww = 0; ww < NW; ++ww) {
                float e = __expf(pS[ww][0] - M);
                den += e * pS[ww][1];
                num += e * pS[ww][2 + t];
                s1  += pS[ww][66 + t];
            }
            out[(size_t)b*(NH*ND2) + h*ND2 + t] = num * __fdividef(1.f, den) + 1e-7f * s1;
        }
        __syncthreads();                        // wS staged & merge done
    }
}

extern "C" void kernel_launch(void* const* d_in, const int* in_sizes, int n_in,
                              void* d_out, int out_size, void* d_ws, size_t ws_size,
                              hipStream_t stream) {
    const float* query = (const float*)d_in[0];
    const float* fact  = (const float*)d_in[1];
    const int*   maskp = (const int*)d_in[2];
    const float* mmc   = (const float*)d_in[3];
    const float* Wq1 = (const float*)d_in[4];
    const float* bq1 = (const float*)d_in[5];
    const float* Wq2 = (const float*)d_in[6];
    const float* bq2 = (const float*)d_in[7];
    const float* Wf1 = (const float*)d_in[8];
    const float* bf1 = (const float*)d_in[9];
    const float* Wf2 = (const float*)d_in[10];
    const float* bf2 = (const float*)d_in[11];
    const float* Wv1 = (const float*)d_in[12];
    const float* bv1 = (const float*)d_in[13];
    const float* Wv2 = (const float*)d_in[14];
    const float* bv2 = (const float*)d_in[15];
    const float* tau1 = (const float*)d_in[16];
    const float* tau2 = (const float*)d_in[17];

    char* ws = (char*)d_ws;
    float*          WQC  = (float*)(ws + OFF_WQC);
    float*          BQC  = (float*)(ws + OFF_BQC);
    float*          FQ   = (float*)(ws + OFF_FQ);
    __hip_bfloat16* WIMG = (__hip_bfloat16*)(ws + OFF_WIMG);
    float*          BFC  = (float*)(ws + OFF_BFC);
    float*          BVC  = (float*)(ws + OFF_BVC);

    k_combine<<<771, 256, 0, stream>>>(Wq1, bq1, Wq2, bq2, Wf1, bf1, Wf2, bf2,
                                       Wv1, bv1, Wv2, bv2, WQC, BQC, WIMG, BFC, BVC);
    k_fq<<<NB/2, 256, 0, stream>>>(query, WQC, BQC, FQ);
    k_main<<<NB, NT, 0, stream>>>(fact, maskp, mmc, tau1, tau2, FQ, BFC, BVC, WIMG,
                                  (float*)d_out);
}